// Round 11
// baseline (173.056 us; speedup 1.0000x reference)
//
#include <hip/hip_runtime.h>
#include <hip/hip_bf16.h>
#include <cstdint>
#include <cstddef>

#define NV    8192   // nodes
#define KIN   512    // in features
#define MOUT  128    // out features
#define LOG2E 1.4426950408889634f
#define MSTRIDE 1032 // mask row stride bytes: 128 tiles*8 + 8 pad (258 dwords, %32==2 -> conflict-free)

typedef __attribute__((ext_vector_type(4))) float f32x4;
typedef __attribute__((ext_vector_type(8))) short short8;

__device__ __forceinline__ float elu1(float x) { return x > 0.f ? x : expm1f(x); }

__device__ __forceinline__ unsigned int pkbf2(float a, float b) {
  union { __hip_bfloat162 h2; unsigned int u; } r;
  r.h2 = __float22bfloat162_rn(make_float2(a, b));
  return r.u;
}

// ---------------- kernel 1: wh1/wh2 (log2-scaled) + fragB (bf16, MFMA-fragment order) ----------------
// fragB[jt][cg][ks][lane][e] = bf16(wh[jt*64+ks*32+(lane>>4)*8+e][cg*16+(lane&15)])
__global__ __launch_bounds__(256) void k_wh(const float* __restrict__ h,
                                            const float* __restrict__ w,
                                            const float* __restrict__ a1,
                                            const float* __restrict__ a2,
                                            unsigned short* __restrict__ fragB,
                                            float* __restrict__ wh1,
                                            float* __restrict__ wh2) {
  __shared__ __align__(16) float hT[64][36];
  __shared__ __align__(16) float wT[64][128];
  const int t = threadIdx.x;
  const int row0 = blockIdx.x * 32;
  const int hr = t >> 3, hu = t & 7;
  const int wc = t >> 1, whalf = t & 1;
  const int cg = t & 31, rg = t >> 5;
  const int c0 = cg * 4, r0 = rg * 4;
  float acc[4][4] = {};

  for (int kt = 0; kt < 8; ++kt) {
    const int k0 = kt * 64;
    __syncthreads();
#pragma unroll
    for (int v = 0; v < 8; ++v)
      hT[hu + 8 * v][hr] = h[(size_t)(row0 + hr) * KIN + k0 + hu + 8 * v];
#pragma unroll
    for (int mv = 0; mv < 8; ++mv) {
      const float4 wv4 = *(const float4*)&w[(size_t)wc * KIN + k0 + whalf * 32 + mv * 4];
      wT[whalf * 32 + mv * 4 + 0][wc] = wv4.x;
      wT[whalf * 32 + mv * 4 + 1][wc] = wv4.y;
      wT[whalf * 32 + mv * 4 + 2][wc] = wv4.z;
      wT[whalf * 32 + mv * 4 + 3][wc] = wv4.w;
    }
    __syncthreads();
#pragma unroll 8
    for (int kk = 0; kk < 64; ++kk) {
      const float4 hv = *(const float4*)&hT[kk][r0];
      const float4 wv4 = *(const float4*)&wT[kk][c0];
      const float hvv[4] = {hv.x, hv.y, hv.z, hv.w};
      const float wvv[4] = {wv4.x, wv4.y, wv4.z, wv4.w};
#pragma unroll
      for (int i = 0; i < 4; ++i)
#pragma unroll
        for (int j = 0; j < 4; ++j)
          acc[i][j] = fmaf(hvv[i], wvv[j], acc[i][j]);
    }
  }

  // fragB store straight from accumulators
  {
    const size_t jt = (size_t)(row0 >> 6);
    const int ks = (row0 >> 5) & 1;
    const int lg = rg >> 1, ebase = (rg & 1) * 4;
    const int cgf = cg >> 2;
    const size_t fbase = (((jt * 8 + cgf) * 2 + ks) * 64 + lg * 16) * 8 + ebase;
#pragma unroll
    for (int j = 0; j < 4; ++j) {
      const int l15 = (cg & 3) * 4 + j;
      uint2 o;
      o.x = pkbf2(acc[0][j], acc[1][j]);
      o.y = pkbf2(acc[2][j], acc[3][j]);
      *(uint2*)&fragB[fbase + (size_t)l15 * 8] = o;
    }
  }

  const float4 a1v = *(const float4*)&a1[c0];
  const float4 a2v = *(const float4*)&a2[c0];
#pragma unroll
  for (int i = 0; i < 4; ++i) {
    float s1 = acc[i][0] * a1v.x + acc[i][1] * a1v.y + acc[i][2] * a1v.z + acc[i][3] * a1v.w;
    float s2 = acc[i][0] * a2v.x + acc[i][1] * a2v.y + acc[i][2] * a2v.z + acc[i][3] * a2v.w;
#pragma unroll
    for (int off = 16; off > 0; off >>= 1) {
      s1 += __shfl_down(s1, off, 32);
      s2 += __shfl_down(s2, off, 32);
    }
    if (cg == 0) {
      wh1[row0 + r0 + i] = s1 * LOG2E;
      wh2[row0 + r0 + i] = s2 * LOG2E;
    }
  }
}

// ---- staging helpers: action k (0..7) of chunk c stages row wv*4+(k>>1), 4 KB sub-slice (k&1).
// One action = one contiguous 4 KB wave-burst (lane covers 16 consecutive ints).
__device__ __forceinline__ void issue_sub(const int* __restrict__ abase, int wv, int c,
                                          int k, int lane, int4 (&d)[4]) {
  const int row = wv * 4 + (k >> 1);
  const int* p = abase + (size_t)row * NV + c * 2048 + (k & 1) * 1024 + lane * 16;
  d[0] = *(const int4*)(p);
  d[1] = *(const int4*)(p + 4);
  d[2] = *(const int4*)(p + 8);
  d[3] = *(const int4*)(p + 12);
}

__device__ __forceinline__ void write_sub(char* sm, int wv, int c, int k, int lane,
                                          const int4 (&s)[4]) {
  const int row = wv * 4 + (k >> 1);
  const int tile = c * 32 + (k & 1) * 16 + (lane >> 2);
  unsigned int us = 0;
#pragma unroll
  for (int m = 0; m < 4; ++m) {
    us |= (unsigned)(s[m].x & 1) << (4 * m);
    us |= (unsigned)(s[m].y & 1) << (4 * m + 1);
    us |= (unsigned)(s[m].z & 1) << (4 * m + 2);
    us |= (unsigned)(s[m].w & 1) << (4 * m + 3);
  }
  *(unsigned short*)&sm[row * MSTRIDE + tile * 8 + (lane & 3) * 2] = (unsigned short)us;
}

// ---------------- kernel 2: full-row attention (16 rows/block, full j-range) ----------------
// grid 512 x 256 (2 blocks/CU). Wave wv owns col-quarter wv*32..+31 for all 16 rows.
// adj streamed as long sequential per-row bursts (fill-kernel pattern, ~2k streams);
// chunk-pipelined into LDS masks. Complete denominator in-block (ones-column MFMA,
// lane-local at epilogue) -> final normalize+ELU+store, no partials, no combine pass.
__global__ __launch_bounds__(256) void k_attn(const unsigned short* __restrict__ fragB,
                                              const int* __restrict__ adj,
                                              const float* __restrict__ wh1l,
                                              const float* __restrict__ wh2l,
                                              float* __restrict__ out) {
  __shared__ char smask[16 * MSTRIDE];
  const int t = threadIdx.x;
  const int i0 = blockIdx.x * 16;
  const int lane = t & 63, wv = t >> 6;
  const int l15 = lane & 15, lg = lane >> 4;
  const int* abase = adj + (size_t)i0 * NV;

  int4 ga[4], gb[4];
  // ---- prologue: stage chunk 0 (tiles 0..31) ----
  issue_sub(abase, wv, 0, 0, lane, ga);
  issue_sub(abase, wv, 0, 1, lane, gb);
#pragma unroll
  for (int k = 2; k < 8; ++k) {
    if (k & 1) { write_sub(smask, wv, 0, k - 2, lane, gb); issue_sub(abase, wv, 0, k, lane, gb); }
    else       { write_sub(smask, wv, 0, k - 2, lane, ga); issue_sub(abase, wv, 0, k, lane, ga); }
  }
  write_sub(smask, wv, 0, 6, lane, ga);
  write_sub(smask, wv, 0, 7, lane, gb);

  // ---- compute setup ----
  const float wh1r = wh1l[i0 + l15];
  const char* mrow = smask + l15 * MSTRIDE;
  const float* w2base = wh2l + lg * 8;
  const unsigned short* bb = fragB + (size_t)(wv * 2) * 1024 + lane * 8;

  f32x4 acc0 = {}, acc1 = {}, accs = {};
  short8 onesf;
#pragma unroll
  for (int e = 0; e < 8; ++e) onesf[e] = (short)0x3F80;  // bf16 1.0

  for (int q = 0; q < 4; ++q) {
    __syncthreads();   // chunk q's masks visible
#pragma unroll 4
    for (int tt = 0; tt < 32; ++tt) {
      const int T = q * 32 + tt;
      // stage chunk q+1: one action per 4 tiles (write action k-2, issue action k)
      if (q < 3 && (tt & 3) == 0) {
        const int k = tt >> 2;
        if (k & 1) {
          if (k >= 2) write_sub(smask, wv, q + 1, k - 2, lane, gb);
          issue_sub(abase, wv, q + 1, k, lane, gb);
        } else {
          if (k >= 2) write_sub(smask, wv, q + 1, k - 2, lane, ga);
          issue_sub(abase, wv, q + 1, k, lane, ga);
        }
      }
      // tile loads (fragB L2-resident: full 2 MB shared by all blocks)
      const unsigned short* bp = bb + (size_t)T * 8192;
      const short8 bf00 = *(const short8*)(bp);           // cgl0 ks0
      const short8 bf01 = *(const short8*)(bp + 512);     // cgl0 ks1
      const short8 bf10 = *(const short8*)(bp + 1024);    // cgl1 ks0
      const short8 bf11 = *(const short8*)(bp + 1536);    // cgl1 ks1
      const uint2 m2 = *(const uint2*)&mrow[T * 8];
      const float* w2p = w2base + T * 64;
      const float4 wq0 = *(const float4*)(w2p);
      const float4 wq1 = *(const float4*)(w2p + 4);
      const float4 wq2 = *(const float4*)(w2p + 32);
      const float4 wq3 = *(const float4*)(w2p + 36);
      const unsigned int m8a = (m2.x >> (8 * lg)) & 0xFFu;  // ks0 bits
      const unsigned int m8b = (m2.y >> (8 * lg)) & 0xFFu;  // ks1 bits

      // P compute (log2-domain): 16 rows' worth per wave (x: ks0, y: ks1)
      const float wA[8] = {wq0.x, wq0.y, wq0.z, wq0.w, wq1.x, wq1.y, wq1.z, wq1.w};
      const float wB[8] = {wq2.x, wq2.y, wq2.z, wq2.w, wq3.x, wq3.y, wq3.z, wq3.w};
      union { short8 s8; unsigned int u[4]; } p0, p1;
#pragma unroll
      for (int e = 0; e < 4; ++e) {
        float x0 = wh1r + wA[2 * e];
        float x1 = wh1r + wA[2 * e + 1];
        float y0 = wh1r + wB[2 * e];
        float y1 = wh1r + wB[2 * e + 1];
        x0 = fmaxf(x0, 0.01f * x0);
        x1 = fmaxf(x1, 0.01f * x1);
        y0 = fmaxf(y0, 0.01f * y0);
        y1 = fmaxf(y1, 0.01f * y1);
        float px0 = __builtin_amdgcn_exp2f(x0);
        float px1 = __builtin_amdgcn_exp2f(x1);
        float py0 = __builtin_amdgcn_exp2f(y0);
        float py1 = __builtin_amdgcn_exp2f(y1);
        px0 = ((m8a >> (2 * e)) & 1u) ? px0 : 0.f;
        px1 = ((m8a >> (2 * e + 1)) & 1u) ? px1 : 0.f;
        py0 = ((m8b >> (2 * e)) & 1u) ? py0 : 0.f;
        py1 = ((m8b >> (2 * e + 1)) & 1u) ? py1 : 0.f;
        p0.u[e] = pkbf2(px0, px1);
        p1.u[e] = pkbf2(py0, py1);
      }
      // MFMA accumulate + ones-column row sums
      acc0 = __builtin_amdgcn_mfma_f32_16x16x32_bf16(p0.s8, bf00, acc0, 0, 0, 0);
      acc1 = __builtin_amdgcn_mfma_f32_16x16x32_bf16(p0.s8, bf10, acc1, 0, 0, 0);
      accs = __builtin_amdgcn_mfma_f32_16x16x32_bf16(p0.s8, onesf, accs, 0, 0, 0);
      acc0 = __builtin_amdgcn_mfma_f32_16x16x32_bf16(p1.s8, bf01, acc0, 0, 0, 0);
      acc1 = __builtin_amdgcn_mfma_f32_16x16x32_bf16(p1.s8, bf11, acc1, 0, 0, 0);
      accs = __builtin_amdgcn_mfma_f32_16x16x32_bf16(p1.s8, onesf, accs, 0, 0, 0);
    }
    // finish chunk q+1 staging (actions 6,7 loaded at tt=24,28)
    if (q < 3) {
      write_sub(smask, wv, q + 1, 6, lane, ga);
      write_sub(smask, wv, q + 1, 7, lane, gb);
    }
  }

  // ---- epilogue: accs[r] IS row (lg*4+r)'s denominator (same in every lane of the lg group)
#pragma unroll
  for (int r = 0; r < 4; ++r) {
    const float inv = 1.f / accs[r];
    const size_t ob = (size_t)(i0 + lg * 4 + r) * MOUT + wv * 32 + l15;
    out[ob] = elu1(acc0[r] * inv);
    out[ob + 16] = elu1(acc1[r] * inv);
  }
}

extern "C" void kernel_launch(void* const* d_in, const int* in_sizes, int n_in,
                              void* d_out, int out_size, void* d_ws, size_t ws_size,
                              hipStream_t stream) {
  const float* h  = (const float*)d_in[0];
  const int* adj  = (const int*)d_in[1];
  const float* w  = (const float*)d_in[2];
  const float* a1 = (const float*)d_in[3];
  const float* a2 = (const float*)d_in[4];
  float* out = (float*)d_out;

  char* ws = (char*)d_ws;
  // layout: [fragB 2MB][wh1 32KB][wh2 32KB]
  unsigned short* fragB = (unsigned short*)ws;
  size_t off = (size_t)MOUT * NV * 2;
  float* wh1 = (float*)(ws + off); off += (size_t)NV * 4;
  float* wh2 = (float*)(ws + off);

  k_wh<<<NV / 32, 256, 0, stream>>>(h, w, a1, a2, fragB, wh1, wh2);
  k_attn<<<NV / 16, 256, 0, stream>>>(fragB, adj, wh1, wh2, out);
}

// Round 12
// 134.475 us; speedup vs baseline: 1.2869x; 1.2869x over previous
//
#include <hip/hip_runtime.h>
#include <hip/hip_bf16.h>
#include <cstdint>
#include <cstddef>

#define NV    8192   // nodes
#define KIN   512    // in features
#define MOUT  128    // out features
#define LOG2E 1.4426950408889634f

typedef __attribute__((ext_vector_type(4))) float f32x4;
typedef __attribute__((ext_vector_type(8))) short short8;

__device__ __forceinline__ float elu1(float x) { return x > 0.f ? x : expm1f(x); }

__device__ __forceinline__ unsigned int pkbf2(float a, float b) {
  union { __hip_bfloat162 h2; unsigned int u; } r;
  r.h2 = __float22bfloat162_rn(make_float2(a, b));
  return r.u;
}

// ---------------- kernel 1: wh1/wh2 (log2-scaled) + fragB (bf16, MFMA-fragment order) ----------------
// fragB[jt][cg][ks][lane][e] = bf16(wh[jt*64+ks*32+(lane>>4)*8+e][cg*16+(lane&15)])
__global__ __launch_bounds__(256) void k_wh(const float* __restrict__ h,
                                            const float* __restrict__ w,
                                            const float* __restrict__ a1,
                                            const float* __restrict__ a2,
                                            unsigned short* __restrict__ fragB,
                                            float* __restrict__ wh1,
                                            float* __restrict__ wh2) {
  __shared__ __align__(16) float hT[64][36];
  __shared__ __align__(16) float wT[64][128];
  const int t = threadIdx.x;
  const int row0 = blockIdx.x * 32;
  const int hr = t >> 3, hu = t & 7;
  const int wc = t >> 1, whalf = t & 1;
  const int cg = t & 31, rg = t >> 5;
  const int c0 = cg * 4, r0 = rg * 4;
  float acc[4][4] = {};

  for (int kt = 0; kt < 8; ++kt) {
    const int k0 = kt * 64;
    __syncthreads();
#pragma unroll
    for (int v = 0; v < 8; ++v)
      hT[hu + 8 * v][hr] = h[(size_t)(row0 + hr) * KIN + k0 + hu + 8 * v];
#pragma unroll
    for (int mv = 0; mv < 8; ++mv) {
      const float4 wv4 = *(const float4*)&w[(size_t)wc * KIN + k0 + whalf * 32 + mv * 4];
      wT[whalf * 32 + mv * 4 + 0][wc] = wv4.x;
      wT[whalf * 32 + mv * 4 + 1][wc] = wv4.y;
      wT[whalf * 32 + mv * 4 + 2][wc] = wv4.z;
      wT[whalf * 32 + mv * 4 + 3][wc] = wv4.w;
    }
    __syncthreads();
#pragma unroll 8
    for (int kk = 0; kk < 64; ++kk) {
      const float4 hv = *(const float4*)&hT[kk][r0];
      const float4 wv4 = *(const float4*)&wT[kk][c0];
      const float hvv[4] = {hv.x, hv.y, hv.z, hv.w};
      const float wvv[4] = {wv4.x, wv4.y, wv4.z, wv4.w};
#pragma unroll
      for (int i = 0; i < 4; ++i)
#pragma unroll
        for (int j = 0; j < 4; ++j)
          acc[i][j] = fmaf(hvv[i], wvv[j], acc[i][j]);
    }
  }

  // fragB store straight from accumulators
  {
    const size_t jt = (size_t)(row0 >> 6);
    const int ks = (row0 >> 5) & 1;
    const int lg = rg >> 1, ebase = (rg & 1) * 4;
    const int cgf = cg >> 2;
    const size_t fbase = (((jt * 8 + cgf) * 2 + ks) * 64 + lg * 16) * 8 + ebase;
#pragma unroll
    for (int j = 0; j < 4; ++j) {
      const int l15 = (cg & 3) * 4 + j;
      uint2 o;
      o.x = pkbf2(acc[0][j], acc[1][j]);
      o.y = pkbf2(acc[2][j], acc[3][j]);
      *(uint2*)&fragB[fbase + (size_t)l15 * 8] = o;
    }
  }

  const float4 a1v = *(const float4*)&a1[c0];
  const float4 a2v = *(const float4*)&a2[c0];
#pragma unroll
  for (int i = 0; i < 4; ++i) {
    float s1 = acc[i][0] * a1v.x + acc[i][1] * a1v.y + acc[i][2] * a1v.z + acc[i][3] * a1v.w;
    float s2 = acc[i][0] * a2v.x + acc[i][1] * a2v.y + acc[i][2] * a2v.z + acc[i][3] * a2v.w;
#pragma unroll
    for (int off = 16; off > 0; off >>= 1) {
      s1 += __shfl_down(s1, off, 32);
      s2 += __shfl_down(s2, off, 32);
    }
    if (cg == 0) {
      wh1[row0 + r0 + i] = s1 * LOG2E;
      wh2[row0 + r0 + i] = s2 * LOG2E;
    }
  }
}

// ---------------- kernel 2: adj-pack + attention partials (R9 structure, more slabs) ----------------
// grid (128, S) x 256, S in {8,16}. 64-row blocks; wave = 32 rows x 64 cols (2 A-frags
// per B-frag reuse). Phase 0: pack block's 64-row x ntiles*64 adj slice into LDS mask
// via dense sequential wave-bursts. Phase 1: L2-only tile loop, 1-deep prefetch, no
// per-tile barriers. S=16 doubles resident blocks (8/CU -> 32 waves/CU): R4->R11 data
// shows resident-wave count is the only lever that tracks dur for this latency-bound loop.
__global__ __launch_bounds__(256) void k_attn_p(const unsigned short* __restrict__ fragB,
                                                const int* __restrict__ adj,
                                                const float* __restrict__ wh1l,
                                                const float* __restrict__ wh2l,
                                                float* __restrict__ out_p,
                                                float* __restrict__ psum_p,
                                                int ntiles) {
  __shared__ char smask[64 * 136];        // [row][tile] uint2 mask; stride = ntiles*8+8
  const int t = threadIdx.x;
  const int i0 = blockIdx.x * 64;
  const int jbase = blockIdx.y * ntiles * 64;
  const int lane = t & 63, wv = t >> 6;
  const int ih = wv & 1, ch = wv >> 1;
  const int l15 = lane & 15, lg = lane >> 4;
  const int mstride = ntiles * 8 + 8;     // 136 (ntiles=16) or 72 (ntiles=8); dwords%32=2 -> conflict-free

  const int* abase = adj + (size_t)i0 * NV + jbase;

  // ---- phase 0: pack adj slice -> LDS bitmask (wave owns 16 rows, sequential bursts) ----
  if (ntiles == 16) {
    for (int rr = 0; rr < 16; ++rr) {
      const int r = wv * 16 + rr;
      const int* rp = abase + (size_t)r * NV + lane * 16;   // lane: 16 consecutive ints
      unsigned int m = 0;
#pragma unroll
      for (int p = 0; p < 4; ++p) {
        const int4 v = *(const int4*)(rp + p * 4);
        m |= ((unsigned)(v.x & 1) << (4 * p))     | ((unsigned)(v.y & 1) << (4 * p + 1)) |
             ((unsigned)(v.z & 1) << (4 * p + 2)) | ((unsigned)(v.w & 1) << (4 * p + 3));
      }
      *(unsigned short*)&smask[r * 136 + (lane >> 2) * 8 + (lane & 3) * 2] = (unsigned short)m;
    }
  } else {  // ntiles == 8
    for (int rr = 0; rr < 16; ++rr) {
      const int r = wv * 16 + rr;
      const int* rp = abase + (size_t)r * NV + lane * 8;    // lane: 8 consecutive ints
      unsigned int m = 0;
#pragma unroll
      for (int p = 0; p < 2; ++p) {
        const int4 v = *(const int4*)(rp + p * 4);
        m |= ((unsigned)(v.x & 1) << (4 * p))     | ((unsigned)(v.y & 1) << (4 * p + 1)) |
             ((unsigned)(v.z & 1) << (4 * p + 2)) | ((unsigned)(v.w & 1) << (4 * p + 3));
      }
      smask[r * 72 + lane] = (char)m;   // tile=lane>>3, byte=(lane&7) -> offset == lane
    }
  }
  __syncthreads();

  // ---- phase 1 ----
  const int rb = ih * 32;
  const float wh1a = wh1l[i0 + rb + l15];
  const float wh1b = wh1l[i0 + rb + 16 + l15];
  const char* mrowa = smask + (rb + l15) * mstride;
  const char* mrowb = smask + (rb + 16 + l15) * mstride;
  const unsigned short* bptr = fragB + (size_t)(jbase >> 6) * 8192 + ch * 4096 + lane * 8;
  const float* w2ptr = wh2l + jbase + lg * 8;

  f32x4 acc[2][4] = {};
  f32x4 accs[2] = {};
  short8 onesf;
#pragma unroll
  for (int e = 0; e < 8; ++e) onesf[e] = (short)0x3F80;  // bf16 1.0

  uint2 m2a = *(const uint2*)&mrowa[0];
  uint2 m2b = *(const uint2*)&mrowb[0];
  short8 bf[8];
#pragma unroll
  for (int ks = 0; ks < 2; ++ks)
#pragma unroll
    for (int cgl = 0; cgl < 4; ++cgl)
      bf[ks * 4 + cgl] = *(const short8*)(bptr + cgl * 1024 + ks * 512);
  bptr += 8192;

  for (int it = 0; it < ntiles; ++it) {
    const unsigned int m16a = ((m2a.x >> (8 * lg)) & 0xFFu) |
                              (((m2a.y >> (8 * lg)) & 0xFFu) << 8);
    const unsigned int m16b = ((m2b.x >> (8 * lg)) & 0xFFu) |
                              (((m2b.y >> (8 * lg)) & 0xFFu) << 8);
    const float4 wq0 = *(const float4*)(w2ptr);
    const float4 wq1 = *(const float4*)(w2ptr + 4);
    const float4 wq2 = *(const float4*)(w2ptr + 32);
    const float4 wq3 = *(const float4*)(w2ptr + 36);
    w2ptr += 64;

    short8 afa[2], afb[2];
#pragma unroll
    for (int ks = 0; ks < 2; ++ks) {
      const float4 wa = ks ? wq2 : wq0;
      const float4 wb = ks ? wq3 : wq1;
      const float w2v[8] = {wa.x, wa.y, wa.z, wa.w, wb.x, wb.y, wb.z, wb.w};
      union { short8 s8; unsigned int u[4]; } pka, pkb;
#pragma unroll
      for (int e = 0; e < 4; ++e) {
        const float x0 = wh1a + w2v[2 * e];
        const float x1 = wh1a + w2v[2 * e + 1];
        const float y0 = wh1b + w2v[2 * e];
        const float y1 = wh1b + w2v[2 * e + 1];
        const float lx0 = fmaxf(x0, 0.01f * x0);
        const float lx1 = fmaxf(x1, 0.01f * x1);
        const float ly0 = fmaxf(y0, 0.01f * y0);
        const float ly1 = fmaxf(y1, 0.01f * y1);
        float px0 = __builtin_amdgcn_exp2f(lx0);
        float px1 = __builtin_amdgcn_exp2f(lx1);
        float py0 = __builtin_amdgcn_exp2f(ly0);
        float py1 = __builtin_amdgcn_exp2f(ly1);
        px0 = ((m16a >> (ks * 8 + 2 * e)) & 1u) ? px0 : 0.f;
        px1 = ((m16a >> (ks * 8 + 2 * e + 1)) & 1u) ? px1 : 0.f;
        py0 = ((m16b >> (ks * 8 + 2 * e)) & 1u) ? py0 : 0.f;
        py1 = ((m16b >> (ks * 8 + 2 * e + 1)) & 1u) ? py1 : 0.f;
        pka.u[e] = pkbf2(px0, px1);
        pkb.u[e] = pkbf2(py0, py1);
      }
      afa[ks] = pka.s8;
      afb[ks] = pkb.s8;
    }
    // prefetch next tile's masks
    if (it + 1 < ntiles) {
      m2a = *(const uint2*)&mrowa[(it + 1) * 8];
      m2b = *(const uint2*)&mrowb[(it + 1) * 8];
    }
#pragma unroll
    for (int ks = 0; ks < 2; ++ks) {
      acc[0][0] = __builtin_amdgcn_mfma_f32_16x16x32_bf16(afa[ks], bf[ks * 4 + 0], acc[0][0], 0, 0, 0);
      acc[0][1] = __builtin_amdgcn_mfma_f32_16x16x32_bf16(afa[ks], bf[ks * 4 + 1], acc[0][1], 0, 0, 0);
      acc[0][2] = __builtin_amdgcn_mfma_f32_16x16x32_bf16(afa[ks], bf[ks * 4 + 2], acc[0][2], 0, 0, 0);
      acc[0][3] = __builtin_amdgcn_mfma_f32_16x16x32_bf16(afa[ks], bf[ks * 4 + 3], acc[0][3], 0, 0, 0);
      accs[0]   = __builtin_amdgcn_mfma_f32_16x16x32_bf16(afa[ks], onesf, accs[0], 0, 0, 0);
      acc[1][0] = __builtin_amdgcn_mfma_f32_16x16x32_bf16(afb[ks], bf[ks * 4 + 0], acc[1][0], 0, 0, 0);
      acc[1][1] = __builtin_amdgcn_mfma_f32_16x16x32_bf16(afb[ks], bf[ks * 4 + 1], acc[1][1], 0, 0, 0);
      acc[1][2] = __builtin_amdgcn_mfma_f32_16x16x32_bf16(afb[ks], bf[ks * 4 + 2], acc[1][2], 0, 0, 0);
      acc[1][3] = __builtin_amdgcn_mfma_f32_16x16x32_bf16(afb[ks], bf[ks * 4 + 3], acc[1][3], 0, 0, 0);
      accs[1]   = __builtin_amdgcn_mfma_f32_16x16x32_bf16(afb[ks], onesf, accs[1], 0, 0, 0);
    }
    // prefetch next tile's B fragments
    if (it + 1 < ntiles) {
#pragma unroll
      for (int ks = 0; ks < 2; ++ks)
#pragma unroll
        for (int cgl = 0; cgl < 4; ++cgl)
          bf[ks * 4 + cgl] = *(const short8*)(bptr + cgl * 1024 + ks * 512);
      bptr += 8192;
    }
  }

  // psum via ones-column: lane(l15=0,lg) reg r holds rowsum[rg*16 + lg*4 + r]
  if (ch == 0 && l15 == 0) {
#pragma unroll
    for (int rg = 0; rg < 2; ++rg)
#pragma unroll
      for (int r = 0; r < 4; ++r)
        psum_p[(size_t)blockIdx.y * NV + i0 + rb + rg * 16 + lg * 4 + r] = accs[rg][r];
  }

  // unnormalized partial tiles (C/D: col=l15, row=lg*4+r)
#pragma unroll
  for (int rg = 0; rg < 2; ++rg) {
    const size_t ob = ((size_t)blockIdx.y * NV + i0 + rb + rg * 16) * MOUT + ch * 64;
#pragma unroll
    for (int cgl = 0; cgl < 4; ++cgl)
#pragma unroll
      for (int r = 0; r < 4; ++r)
        out_p[ob + (size_t)(lg * 4 + r) * MOUT + cgl * 16 + l15] = acc[rg][cgl][r];
  }
}

// ---------------- kernel 3: combine partials, normalize, ELU ----------------
__global__ __launch_bounds__(256) void k_comb(const float* __restrict__ out_p,
                                              const float* __restrict__ psum_p,
                                              float* __restrict__ out, int S) {
  const int idx = (blockIdx.x * 256 + threadIdx.x) * 4;
  const int n = idx >> 7;  // MOUT = 128
  float denom = 0.f;
  for (int s = 0; s < S; ++s) denom += psum_p[(size_t)s * NV + n];
  float4 acc = {0.f, 0.f, 0.f, 0.f};
  for (int s = 0; s < S; ++s) {
    const float4 v = *(const float4*)&out_p[(size_t)s * NV * MOUT + idx];
    acc.x += v.x; acc.y += v.y; acc.z += v.z; acc.w += v.w;
  }
  const float inv = 1.f / denom;
  float4 o;
  o.x = elu1(acc.x * inv);
  o.y = elu1(acc.y * inv);
  o.z = elu1(acc.z * inv);
  o.w = elu1(acc.w * inv);
  *(float4*)&out[idx] = o;
}

extern "C" void kernel_launch(void* const* d_in, const int* in_sizes, int n_in,
                              void* d_out, int out_size, void* d_ws, size_t ws_size,
                              hipStream_t stream) {
  const float* h  = (const float*)d_in[0];
  const int* adj  = (const int*)d_in[1];
  const float* w  = (const float*)d_in[2];
  const float* a1 = (const float*)d_in[3];
  const float* a2 = (const float*)d_in[4];
  float* out = (float*)d_out;

  char* ws = (char*)d_ws;
  // layout: [fragB 2MB][wh1 32KB][wh2 32KB][psum_p 512KB][out_p S*4MB]
  unsigned short* fragB = (unsigned short*)ws;
  size_t off = (size_t)MOUT * NV * 2;
  float* wh1 = (float*)(ws + off); off += (size_t)NV * 4;
  float* wh2 = (float*)(ws + off); off += (size_t)NV * 4;
  float* psum_p = (float*)(ws + off); off += (size_t)16 * NV * 4;
  float* out_p = (float*)(ws + off);

  int S = 16;
  while (S > 8 && off + (size_t)S * NV * MOUT * 4 > ws_size) S >>= 1;
  const int ntiles = 128 / S;

  k_wh<<<NV / 32, 256, 0, stream>>>(h, w, a1, a2, fragB, wh1, wh2);
  k_attn_p<<<dim3(NV / 64, S), 256, 0, stream>>>(fragB, adj, wh1, wh2, out_p, psum_p, ntiles);
  k_comb<<<(NV * MOUT / 4) / 256, 256, 0, stream>>>(out_p, psum_p, out, S);
}